// Round 12
// baseline (244.970 us; speedup 1.0000x reference)
//
#include <hip/hip_runtime.h>
#include <hip/hip_fp16.h>
#include <math.h>

#define N_NODES 50000
#define N_EDGES 800000
#define N_GRAPHS 1024
#define DIM 64
#define PAD 64           // padded CSR slots per destination (max in-degree ~45)
#define ZROW N_NODES     // index of the guaranteed-zero row in t'
#define HALF_N 25000     // src-half boundary: each th half = 3.2MB (fits one L2)

// bucketed CSR build: 256 dests per bucket
#define BSHIFT 8
#define BDEST 256
#define NB 196           // ceil(50000/256)
#define CAP_B 6144       // bucket capacity (mean 4096, +32 sigma)
#define EPB 4096         // edges per phase-1 block (196 blocks)

typedef int      v4i __attribute__((ext_vector_type(4)));
typedef float    v4f __attribute__((ext_vector_type(4)));
typedef unsigned v2u __attribute__((ext_vector_type(2)));
typedef unsigned v4u __attribute__((ext_vector_type(4)));

__device__ __forceinline__ int4 ntld4i(const int* p) {
    v4i v = __builtin_nontemporal_load((const v4i*)p);
    return make_int4(v[0], v[1], v[2], v[3]);
}
// nt STORES for producer->cross-XCD-consumer buffers (r9: small win)
__device__ __forceinline__ void ntst2u(uint2* p, uint2 v) {
    v2u w; w[0] = v.x; w[1] = v.y;
    __builtin_nontemporal_store(w, (v2u*)p);
}
__device__ __forceinline__ void ntst4u(uint4* p, uint4 v) {
    v4u w; w[0] = v.x; w[1] = v.y; w[2] = v.z; w[3] = v.w;
    __builtin_nontemporal_store(w, (v4u*)p);
}
__device__ __forceinline__ void ntst4f(float4* p, float4 v) {
    v4f w; w[0] = v.x; w[1] = v.y; w[2] = v.z; w[3] = v.w;
    __builtin_nontemporal_store(w, (v4f*)p);
}
__device__ __forceinline__ void ntsth(__half* p, __half v) {
    short s = *(short*)&v;
    __builtin_nontemporal_store(s, (short*)p);
}

// ---------------- phase 1: bucket the edge list, DENSE writes only ----------
// gfx950 lesson (r3/r4/r7): scattered sub-line stores, scattered atomics and
// contended cross-XCD atomics all hit the slow fabric path. The build only
// writes dense contiguous chunks; global atomics are one per block*bucket.

__global__ void fill_p1(const int* __restrict__ row, const int* __restrict__ col,
                        int* __restrict__ bcnt, unsigned* __restrict__ bbuf) {
    __shared__ int hist[NB];
    __shared__ int base[NB];
    int tid = threadIdx.x;
    if (tid < NB) hist[tid] = 0;
    __syncthreads();

    int e0 = blockIdx.x * EPB;
    int bk[16]; int rk[16]; unsigned pk[16];
#pragma unroll
    for (int i = 0; i < 4; ++i) {
        int e4 = e0 + i * 1024 + tid * 4;
        bool ok = e4 < N_EDGES;
        int4 c = ok ? ntld4i(col + e4) : make_int4(0, 0, 0, 0);
        int4 r = ok ? ntld4i(row + e4) : make_int4(0, 0, 0, 0);
        int cc[4] = {c.x, c.y, c.z, c.w};
        int rr[4] = {r.x, r.y, r.z, r.w};
#pragma unroll
        for (int j = 0; j < 4; ++j) {
            int q = i * 4 + j;
            if (ok) {
                bk[q] = cc[j] >> BSHIFT;
                pk[q] = ((unsigned)rr[j] << BSHIFT) | (unsigned)(cc[j] & (BDEST - 1));
                rk[q] = atomicAdd(&hist[bk[q]], 1);
            } else {
                bk[q] = -1; rk[q] = 0; pk[q] = 0;
            }
        }
    }
    __syncthreads();
    if (tid < NB) base[tid] = atomicAdd(&bcnt[tid], hist[tid]);
    __syncthreads();
#pragma unroll
    for (int q = 0; q < 16; ++q) {
        if (bk[q] >= 0) {
            int pos = base[bk[q]] + rk[q];
            if (pos < CAP_B) bbuf[(size_t)bk[q] * CAP_B + pos] = pk[q];
        }
    }
}

// ---------------- phase 2: bucket -> src-half-partitioned padded CSR ---------
// One block per bucket. Lo-half sources (src<HALF_N) pack ascending from slot
// 0; hi-half sources pack descending from slot PAD-1. Each section is padded
// to an 8-slot batch boundary with ZROW sentinels (reads the guaranteed-zero
// row -- one hot line, broadcast-cheap; also removes tail-clamp VALU from the
// gather hot loop). dpk[node] = nbA | nbB<<8 (batch counts per section).

__global__ void fill_p2(const int* __restrict__ bcnt, const unsigned* __restrict__ bbuf,
                        int* __restrict__ ideg, unsigned short* __restrict__ dpk,
                        unsigned short* __restrict__ esrc) {
    __shared__ unsigned short srow[BDEST * PAD];   // 32 KB
    __shared__ int llo[BDEST];
    __shared__ int lhi[BDEST];
    int tid = threadIdx.x;
    int b = blockIdx.x;
    llo[tid] = 0;
    lhi[tid] = 0;
    __syncthreads();

    int cnt = min(bcnt[b], CAP_B);
    const unsigned* bp = bbuf + (size_t)b * CAP_B;
    for (int e = tid; e < cnt; e += 256) {
        unsigned u = bp[e];
        int local = u & (BDEST - 1);
        int src = (int)(u >> BSHIFT);
        if (src < HALF_N) {
            int k = atomicAdd(&llo[local], 1);          // LDS atomic
            if (k < PAD) srow[local * PAD + k] = (unsigned short)src;
        } else {
            int k = atomicAdd(&lhi[local], 1);
            if (k < PAD) srow[local * PAD + (PAD - 1 - k)] = (unsigned short)src;
        }
    }
    __syncthreads();

    int dest0 = b << BSHIFT;
    int node = dest0 + tid;
    if (node < N_NODES) {
        int loRaw = llo[tid], hiRaw = lhi[tid];
        int lo = min(loRaw, PAD), hi = min(hiRaw, PAD);
        int nbA = (lo + 7) >> 3;
        int nbB = (hi + 7) >> 3;
        if (nbB > 8 - nbA) nbB = 8 - nbA;          // disjoint-section guard (deg>57: ~never)
        for (int i = lo; i < nbA * 8; ++i) srow[tid * PAD + i] = (unsigned short)ZROW;
        int hiStart = PAD - nbB * 8;
        for (int i = hiStart; i < PAD - hi; ++i) srow[tid * PAD + i] = (unsigned short)ZROW;
        ideg[node] = loRaw + hiRaw;                 // true in-degree (for dinv)
        dpk[node] = (unsigned short)(nbA | (nbB << 8));
    }
    __syncthreads();

    const uint4* s4 = (const uint4*)srow;
#pragma unroll
    for (int i = 0; i < 8; ++i) {
        int idx = tid + 256 * i;
        int local = idx >> 3;
        int n2 = dest0 + local;
        if (n2 < N_NODES)
            ntst4u(&((uint4*)(esrc + (size_t)n2 * PAD))[idx & 7], s4[idx]);
    }
}

// ---------------- dense transforms (t' = dinv * (h @ W), fp16, nt stores) ----

__global__ void gemm9(const float* __restrict__ x, const float* __restrict__ W,
                      const int* __restrict__ ideg, __half* __restrict__ th) {
    __shared__ float Wl[9 * DIM];
    int tid = threadIdx.x;
    if (blockIdx.x == 0 && tid < DIM) th[(size_t)ZROW * DIM + tid] = __float2half(0.0f);
    for (int i = tid; i < 9 * DIM; i += 256) Wl[i] = W[i];
    __syncthreads();
    int node = blockIdx.x * 4 + (tid >> 6);
    int d = tid & 63;
    if (node >= N_NODES) return;
    const float* xr = x + (size_t)node * 9;
    float acc = 0.0f;
#pragma unroll
    for (int k = 0; k < 9; ++k) acc += xr[k] * Wl[k * DIM + d];
    float dv = rsqrtf((float)ideg[node] + 1.0f);
    ntsth(&th[(size_t)node * DIM + d], __float2half(dv * acc));
}

// layers 1-3: 64x64 register-tile GEMM, 64-node tiles, fp16+dinv nt output.
__global__ void gemm64(const float* __restrict__ h, const float* __restrict__ W,
                       const int* __restrict__ ideg, uint2* __restrict__ th2) {
    __shared__ float At[64][68];
    __shared__ float Bl[64][68];
    int tid = threadIdx.x;
    int n0 = blockIdx.x * 64;

    {
        const float4* W4 = (const float4*)W;
#pragma unroll
        for (int i = 0; i < 4; ++i) {
            int idx = tid + 256 * i;
            int k = idx >> 4;
            int d4 = idx & 15;
            float4 v = W4[idx];
            *(float4*)&Bl[k][d4 * 4] = v;
        }
    }
    {
        int node = tid >> 2;
        int seg = tid & 3;
        int gn = n0 + node;
        bool ok = gn < N_NODES;
        const float4* h4 = (const float4*)h;
#pragma unroll
        for (int i = 0; i < 4; ++i) {
            int c4 = seg * 4 + i;
            float4 v = ok ? h4[(size_t)gn * 16 + c4] : make_float4(0.f, 0.f, 0.f, 0.f);
            int d = c4 * 4;
            At[d + 0][node] = v.x;
            At[d + 1][node] = v.y;
            At[d + 2][node] = v.z;
            At[d + 3][node] = v.w;
        }
    }
    __syncthreads();

    int ty = tid >> 4;
    int tx = tid & 15;
    float c00 = 0, c01 = 0, c02 = 0, c03 = 0;
    float c10 = 0, c11 = 0, c12 = 0, c13 = 0;
    float c20 = 0, c21 = 0, c22 = 0, c23 = 0;
    float c30 = 0, c31 = 0, c32 = 0, c33 = 0;
#pragma unroll 8
    for (int k = 0; k < 64; ++k) {
        float4 a = *(const float4*)&At[k][ty * 4];
        float4 b = *(const float4*)&Bl[k][tx * 4];
        c00 += a.x * b.x; c01 += a.x * b.y; c02 += a.x * b.z; c03 += a.x * b.w;
        c10 += a.y * b.x; c11 += a.y * b.y; c12 += a.y * b.z; c13 += a.y * b.w;
        c20 += a.z * b.x; c21 += a.z * b.y; c22 += a.z * b.z; c23 += a.z * b.w;
        c30 += a.w * b.x; c31 += a.w * b.y; c32 += a.w * b.z; c33 += a.w * b.w;
    }
    int gn = n0 + ty * 4;
#define STORE_ROW(r, CA, CB, CC, CD)                                          \
    if (gn + r < N_NODES) {                                                   \
        float dv = rsqrtf((float)ideg[gn + r] + 1.0f);                        \
        __half2 p0 = __floats2half2_rn(dv * CA, dv * CB);                     \
        __half2 p1 = __floats2half2_rn(dv * CC, dv * CD);                     \
        uint2 o;                                                              \
        o.x = *(unsigned*)&p0;                                                \
        o.y = *(unsigned*)&p1;                                                \
        ntst2u(&th2[(size_t)(gn + r) * 16 + tx], o);                          \
    }
    STORE_ROW(0, c00, c01, c02, c03)
    STORE_ROW(1, c10, c11, c12, c13)
    STORE_ROW(2, c20, c21, c22, c23)
    STORE_ROW(3, c30, c31, c32, c33)
#undef STORE_ROW
}

// ---------------- gather + bias + tanh: parity-ordered src-half phases ------
// Identical request structure to r9 (16-lane groups, one full 128B row per
// edge, double-buffered, (256,7)) but batches are sentinel-padded (no tail
// clamp) and ordered by section: even blocks lo-section first, odd blocks
// hi-section first. With round-robin block->XCD dispatch, at any instant
// each XCD parity class's random reads target ONE 3.2MB th half < 4MiB L2
// -> misses become local L2 hits at UNCHANGED request count.

__device__ __forceinline__ float4 h4tof4(uint2 v) {
    __half2 a = *reinterpret_cast<const __half2*>(&v.x);
    __half2 c = *reinterpret_cast<const __half2*>(&v.y);
    float2 fa = __half22float2(a);
    float2 fc = __half22float2(c);
    return make_float4(fa.x, fa.y, fc.x, fc.y);
}

__device__ __forceinline__ void add4(float4& a, const float4& r) {
    a.x += r.x; a.y += r.y; a.z += r.z; a.w += r.w;
}

#define BIDX(K) (((K) < n1) ? (s1 + (K)) : (s2 + (K) - n1))

#define ISSUE(R, K)                                                           \
    {                                                                         \
        uint4 u_ = ep4[BIDX(K)];                                              \
        unsigned ww_[4] = {u_.x, u_.y, u_.z, u_.w};                           \
        _Pragma("unroll")                                                     \
        for (int j = 0; j < 8; ++j) {                                         \
            int s_ = (int)((ww_[j >> 1] >> ((j & 1) * 16)) & 0xffffu);        \
            R[j] = tb[(size_t)s_ * 16];                                       \
        }                                                                     \
    }

#define CONSUME(R)                                                            \
    {                                                                         \
        _Pragma("unroll")                                                     \
        for (int j = 0; j < 8; ++j) {                                         \
            float4 v_ = h4tof4(R[j]);                                         \
            if ((j & 1) == 0) add4(acc0, v_); else add4(acc1, v_);            \
        }                                                                     \
    }

__global__ __launch_bounds__(256, 7)
void gather_tanh(const unsigned short* __restrict__ esrc, const int* __restrict__ ideg,
                 const unsigned short* __restrict__ dpk,
                 const uint2* __restrict__ th2, const float* __restrict__ b,
                 float4* __restrict__ hout4) {
    int tid = threadIdx.x;
    int wid = tid >> 6;
    int lane = tid & 63;
    int sub = lane & 15;   // half4 chunk: dims [4*sub, 4*sub+4)
    int grp = lane >> 4;   // 0..3 -> node
    int node = blockIdx.x * 16 + wid * 4 + grp;  // grid = N_NODES/16 = 3125
    int par = blockIdx.x & 1;                    // XCD parity class

    int deg = ideg[node];                        // true in-degree (dinv only)
    unsigned pk = dpk[node];
    int nbA = pk & 0xff;                         // lo-section batches at [0, nbA)
    int nbB = (pk >> 8) & 0xff;                  // hi-section batches at [8-nbB, 8)
    int hiS = 8 - nbB;
    int n1 = par ? nbB : nbA;                    // first-phase count
    int s1 = par ? hiS : 0;                      // first-phase start
    int s2 = par ? 0 : hiS;                      // second-phase start
    int nbt = nbA + nbB;

    const uint4* ep4 = (const uint4*)(esrc + node * PAD);  // one 128B line
    const uint2* tb = th2 + sub;

    // self-loop + 2 split accumulators
    float4 acc0 = h4tof4(tb[(size_t)node * 16]);
    float4 acc1 = make_float4(0.f, 0.f, 0.f, 0.f);

    uint2 rA[8], rB[8];
    if (nbt > 0) {
        ISSUE(rA, 0)
        int bi = 0;
        while (bi + 2 <= nbt) {
            ISSUE(rB, bi + 1)
            CONSUME(rA)
            if (bi + 2 < nbt) ISSUE(rA, bi + 2)
            CONSUME(rB)
            bi += 2;
        }
        if (bi < nbt) CONSUME(rA)
    }

    float4 acc;
    acc.x = acc0.x + acc1.x;
    acc.y = acc0.y + acc1.y;
    acc.z = acc0.z + acc1.z;
    acc.w = acc0.w + acc1.w;

    float4 bv = ((const float4*)b)[sub];
    float dv = rsqrtf((float)deg + 1.0f);
    float4 res;
    res.x = tanhf(dv * acc.x + bv.x);
    res.y = tanhf(dv * acc.y + bv.y);
    res.z = tanhf(dv * acc.z + bv.z);
    res.w = tanhf(dv * acc.w + bv.w);
    ntst4f(&hout4[(size_t)node * 16 + sub], res);   // consumed by other XCDs
}

// ---------------- pooling + output ----------------

__device__ __forceinline__ int lower_bound(const int* a, int n, int key) {
    int lo = 0, hi = n;
    while (lo < hi) {
        int mid = (lo + hi) >> 1;
        if (a[mid] < key) lo = mid + 1; else hi = mid;
    }
    return lo;
}

__global__ void pool_out(const float* __restrict__ h, const int* __restrict__ batch,
                         const float* __restrict__ Wout, const float* __restrict__ bout,
                         float* __restrict__ out) {
    __shared__ float smax[4][DIM];
    __shared__ float ssum[4][DIM];
    __shared__ int bounds[2];
    int g = blockIdx.x;
    int tid = threadIdx.x, w = tid >> 6, d = tid & 63;
    if (tid == 0) {
        bounds[0] = lower_bound(batch, N_NODES, g);
        bounds[1] = lower_bound(batch, N_NODES, g + 1);
    }
    __syncthreads();
    int start = bounds[0], end = bounds[1];
    float mx = -INFINITY, sum = 0.0f;
    for (int n = start + w; n < end; n += 4) {
        float v = h[(size_t)n * DIM + d];
        mx = fmaxf(mx, v);
        sum += v;
    }
    smax[w][d] = mx;
    ssum[w][d] = sum;
    __syncthreads();
    if (w == 0) {
        mx = fmaxf(fmaxf(smax[0][d], smax[1][d]), fmaxf(smax[2][d], smax[3][d]));
        sum = ssum[0][d] + ssum[1][d] + ssum[2][d] + ssum[3][d];
        float cnt = (float)(end - start);
        float mean = sum / fmaxf(cnt, 1.0f);
        float v = mx * Wout[d] + mean * Wout[DIM + d];
#pragma unroll
        for (int off = 32; off > 0; off >>= 1) v += __shfl_down(v, off, 64);
        if (d == 0) out[g] = v + bout[0];
    }
}

// ---------------- launch ----------------

static inline size_t align256(size_t x) { return (x + 255) & ~(size_t)255; }

extern "C" void kernel_launch(void* const* d_in, const int* in_sizes, int n_in,
                              void* d_out, int out_size, void* d_ws, size_t ws_size,
                              hipStream_t stream) {
    const float* x     = (const float*)d_in[0];
    const int*   ei    = (const int*)d_in[1];
    const int*   batch = (const int*)d_in[2];
    const float* W0    = (const float*)d_in[3];
    const float* b0    = (const float*)d_in[4];
    const float* W1    = (const float*)d_in[5];
    const float* b1    = (const float*)d_in[6];
    const float* W2    = (const float*)d_in[7];
    const float* b2    = (const float*)d_in[8];
    const float* W3    = (const float*)d_in[9];
    const float* b3    = (const float*)d_in[10];
    const float* Wout  = (const float*)d_in[11];
    const float* bout  = (const float*)d_in[12];
    float* out = (float*)d_out;

    const int* row = ei;            // source
    const int* col = ei + N_EDGES;  // destination

    char* ws = (char*)d_ws;
    size_t off = 0;
    int*            ideg = (int*)(ws + off);            off += align256((size_t)N_NODES * 4);
    unsigned short* dpk  = (unsigned short*)(ws + off); off += align256((size_t)N_NODES * 2);
    unsigned short* esrc = (unsigned short*)(ws + off); off += align256((size_t)N_NODES * PAD * 2);
    __half*         th   = (__half*)(ws + off);         off += align256(((size_t)N_NODES + 1) * DIM * 2);
    float*          hA   = (float*)(ws + off);          off += align256((size_t)N_NODES * DIM * 4);
    unsigned*       bbuf = (unsigned*)(ws + off);       off += align256((size_t)NB * CAP_B * 4);
    int*            bcnt = (int*)(ws + off);            off += align256((size_t)NB * 4);
    (void)ws_size;

    const int wave_blocks = N_NODES / 4;                 // 12500 (gemm9)
    const int gath_blocks = N_NODES / 16;                // 3125  (4 nodes/wave)
    const int gemm_blocks = (N_NODES + 63) / 64;         // 782

    // bucketed CSR build (dense writes only, src-half partitioned rows)
    hipMemsetAsync(bcnt, 0, (size_t)NB * 4, stream);
    fill_p1<<<NB, 256, 0, stream>>>(row, col, bcnt, bbuf);
    fill_p2<<<NB, 256, 0, stream>>>(bcnt, bbuf, ideg, dpk, esrc);

    // layer 0 (gemm9 also zero-fills the ZROW of th)
    gemm9<<<wave_blocks, 256, 0, stream>>>(x, W0, ideg, th);
    gather_tanh<<<gath_blocks, 256, 0, stream>>>(esrc, ideg, dpk, (const uint2*)th, b0, (float4*)hA);

    // layers 1-3
    const float* Ws[3] = {W1, W2, W3};
    const float* bs[3] = {b1, b2, b3};
    for (int l = 0; l < 3; ++l) {
        gemm64<<<gemm_blocks, 256, 0, stream>>>(hA, Ws[l], ideg, (uint2*)th);
        gather_tanh<<<gath_blocks, 256, 0, stream>>>(esrc, ideg, dpk, (const uint2*)th, bs[l], (float4*)hA);
    }

    // pooling + output
    pool_out<<<N_GRAPHS, 256, 0, stream>>>(hA, batch, Wout, bout, out);
    (void)out_size; (void)n_in; (void)in_sizes;
}

// Round 13
// 233.282 us; speedup vs baseline: 1.0501x; 1.0501x over previous
//
#include <hip/hip_runtime.h>
#include <hip/hip_fp16.h>
#include <math.h>

#define N_NODES 50000
#define N_EDGES 800000
#define N_GRAPHS 1024
#define DIM 64
#define PAD 64           // padded CSR slots per destination (max in-degree ~45)
#define ZROW N_NODES     // index of the guaranteed-zero row in t'

// bucketed CSR build: 256 dests per bucket
#define BSHIFT 8
#define BDEST 256
#define NB 196           // ceil(50000/256)
#define CAP_B 6144       // bucket capacity (mean 4096, +32 sigma)
#define EPB 4096         // edges per phase-1 block (196 blocks)

typedef int      v4i __attribute__((ext_vector_type(4)));
typedef float    v4f __attribute__((ext_vector_type(4)));
typedef unsigned v2u __attribute__((ext_vector_type(2)));
typedef unsigned v4u __attribute__((ext_vector_type(4)));

__device__ __forceinline__ int4 ntld4i(const int* p) {
    v4i v = __builtin_nontemporal_load((const v4i*)p);
    return make_int4(v[0], v[1], v[2], v[3]);
}
// nt STORES: producer buffers consumed by OTHER XCDs (r9: +5us win) --
// lines land clean in L3 instead of dirty in the producer XCD's L2.
__device__ __forceinline__ void ntst2u(uint2* p, uint2 v) {
    v2u w; w[0] = v.x; w[1] = v.y;
    __builtin_nontemporal_store(w, (v2u*)p);
}
__device__ __forceinline__ void ntst4u(uint4* p, uint4 v) {
    v4u w; w[0] = v.x; w[1] = v.y; w[2] = v.z; w[3] = v.w;
    __builtin_nontemporal_store(w, (v4u*)p);
}
__device__ __forceinline__ void ntst4f(float4* p, float4 v) {
    v4f w; w[0] = v.x; w[1] = v.y; w[2] = v.z; w[3] = v.w;
    __builtin_nontemporal_store(w, (v4f*)p);
}
__device__ __forceinline__ void ntsth(__half* p, __half v) {
    short s = *(short*)&v;
    __builtin_nontemporal_store(s, (short*)p);
}

// ---------------- phase 1: bucket the edge list, DENSE writes only ----------
// gfx950 lesson (r3/r4/r7): scattered sub-line stores, scattered atomics and
// contended cross-XCD atomics all hit the slow fabric path. The build only
// writes dense contiguous chunks; global atomics are one per block*bucket.

__global__ void fill_p1(const int* __restrict__ row, const int* __restrict__ col,
                        int* __restrict__ bcnt, unsigned* __restrict__ bbuf) {
    __shared__ int hist[NB];
    __shared__ int base[NB];
    int tid = threadIdx.x;
    if (tid < NB) hist[tid] = 0;
    __syncthreads();

    int e0 = blockIdx.x * EPB;
    int bk[16]; int rk[16]; unsigned pk[16];
#pragma unroll
    for (int i = 0; i < 4; ++i) {
        int e4 = e0 + i * 1024 + tid * 4;      // N_EDGES % 4 == 0: int4 all-or-nothing
        bool ok = e4 < N_EDGES;
        int4 c = ok ? ntld4i(col + e4) : make_int4(0, 0, 0, 0);
        int4 r = ok ? ntld4i(row + e4) : make_int4(0, 0, 0, 0);
        int cc[4] = {c.x, c.y, c.z, c.w};
        int rr[4] = {r.x, r.y, r.z, r.w};
#pragma unroll
        for (int j = 0; j < 4; ++j) {
            int q = i * 4 + j;
            if (ok) {
                bk[q] = cc[j] >> BSHIFT;
                pk[q] = ((unsigned)rr[j] << BSHIFT) | (unsigned)(cc[j] & (BDEST - 1));
                rk[q] = atomicAdd(&hist[bk[q]], 1);   // LDS atomic: block-local rank
            } else {
                bk[q] = -1; rk[q] = 0; pk[q] = 0;
            }
        }
    }
    __syncthreads();
    if (tid < NB) base[tid] = atomicAdd(&bcnt[tid], hist[tid]);  // claim chunks
    __syncthreads();
#pragma unroll
    for (int q = 0; q < 16; ++q) {
        if (bk[q] >= 0) {
            int pos = base[bk[q]] + rk[q];
            if (pos < CAP_B) bbuf[(size_t)bk[q] * CAP_B + pos] = pk[q];
        }
    }
}

// ---------------- phase 2: bucket -> padded CSR via LDS, full-line writes ----

__global__ void fill_p2(const int* __restrict__ bcnt, const unsigned* __restrict__ bbuf,
                        int* __restrict__ ideg, unsigned short* __restrict__ esrc) {
    __shared__ unsigned short srow[BDEST * PAD];   // 32 KB
    __shared__ int ldeg[BDEST];
    int tid = threadIdx.x;
    int b = blockIdx.x;
    {
        uint4* s4 = (uint4*)srow;                  // 2048 uint4
        for (int i = tid; i < BDEST * PAD / 8; i += 256) s4[i] = make_uint4(0, 0, 0, 0);
        ldeg[tid] = 0;                             // BDEST == blockDim
    }
    __syncthreads();

    int cnt = min(bcnt[b], CAP_B);
    const unsigned* bp = bbuf + (size_t)b * CAP_B;
    for (int e = tid; e < cnt; e += 256) {
        unsigned u = bp[e];
        int local = u & (BDEST - 1);
        int src = (int)(u >> BSHIFT);
        int k = atomicAdd(&ldeg[local], 1);        // LDS atomic
        if (k < PAD) srow[local * PAD + k] = (unsigned short)src;
    }
    __syncthreads();

    int dest0 = b << BSHIFT;
    {
        int node = dest0 + tid;
        if (node < N_NODES) ideg[node] = ldeg[tid];   // true count (pre-clamp)
    }
    const uint4* s4 = (const uint4*)srow;
#pragma unroll
    for (int i = 0; i < 8; ++i) {
        int idx = tid + 256 * i;                   // 0..2047
        int local = idx >> 3;
        int node = dest0 + local;
        if (node < N_NODES)
            ntst4u(&((uint4*)(esrc + (size_t)node * PAD))[idx & 7], s4[idx]);
    }
}

// ---------------- dense transforms (t' = dinv * (h @ W), fp16, nt stores) ----

__global__ void gemm9(const float* __restrict__ x, const float* __restrict__ W,
                      const int* __restrict__ ideg, __half* __restrict__ th) {
    __shared__ float Wl[9 * DIM];
    int tid = threadIdx.x;
    if (blockIdx.x == 0 && tid < DIM) th[(size_t)ZROW * DIM + tid] = __float2half(0.0f);
    for (int i = tid; i < 9 * DIM; i += 256) Wl[i] = W[i];
    __syncthreads();
    int node = blockIdx.x * 4 + (tid >> 6);
    int d = tid & 63;
    if (node >= N_NODES) return;
    const float* xr = x + (size_t)node * 9;
    float acc = 0.0f;
#pragma unroll
    for (int k = 0; k < 9; ++k) acc += xr[k] * Wl[k * DIM + d];
    float dv = rsqrtf((float)ideg[node] + 1.0f);
    ntsth(&th[(size_t)node * DIM + d], __float2half(dv * acc));
}

// layers 1-3: 64x64 register-tile GEMM, 64-node tiles, fp16+dinv nt output.
__global__ void gemm64(const float* __restrict__ h, const float* __restrict__ W,
                       const int* __restrict__ ideg, uint2* __restrict__ th2) {
    __shared__ float At[64][68];
    __shared__ float Bl[64][68];
    int tid = threadIdx.x;
    int n0 = blockIdx.x * 64;

    {
        const float4* W4 = (const float4*)W;
#pragma unroll
        for (int i = 0; i < 4; ++i) {
            int idx = tid + 256 * i;
            int k = idx >> 4;
            int d4 = idx & 15;
            float4 v = W4[idx];
            *(float4*)&Bl[k][d4 * 4] = v;
        }
    }
    {
        int node = tid >> 2;
        int seg = tid & 3;
        int gn = n0 + node;
        bool ok = gn < N_NODES;
        const float4* h4 = (const float4*)h;
#pragma unroll
        for (int i = 0; i < 4; ++i) {
            int c4 = seg * 4 + i;
            float4 v = ok ? h4[(size_t)gn * 16 + c4] : make_float4(0.f, 0.f, 0.f, 0.f);
            int d = c4 * 4;
            At[d + 0][node] = v.x;
            At[d + 1][node] = v.y;
            At[d + 2][node] = v.z;
            At[d + 3][node] = v.w;
        }
    }
    __syncthreads();

    int ty = tid >> 4;
    int tx = tid & 15;
    float c00 = 0, c01 = 0, c02 = 0, c03 = 0;
    float c10 = 0, c11 = 0, c12 = 0, c13 = 0;
    float c20 = 0, c21 = 0, c22 = 0, c23 = 0;
    float c30 = 0, c31 = 0, c32 = 0, c33 = 0;
#pragma unroll 8
    for (int k = 0; k < 64; ++k) {
        float4 a = *(const float4*)&At[k][ty * 4];
        float4 b = *(const float4*)&Bl[k][tx * 4];
        c00 += a.x * b.x; c01 += a.x * b.y; c02 += a.x * b.z; c03 += a.x * b.w;
        c10 += a.y * b.x; c11 += a.y * b.y; c12 += a.y * b.z; c13 += a.y * b.w;
        c20 += a.z * b.x; c21 += a.z * b.y; c22 += a.z * b.z; c23 += a.z * b.w;
        c30 += a.w * b.x; c31 += a.w * b.y; c32 += a.w * b.z; c33 += a.w * b.w;
    }
    int gn = n0 + ty * 4;
#define STORE_ROW(r, CA, CB, CC, CD)                                          \
    if (gn + r < N_NODES) {                                                   \
        float dv = rsqrtf((float)ideg[gn + r] + 1.0f);                        \
        __half2 p0 = __floats2half2_rn(dv * CA, dv * CB);                     \
        __half2 p1 = __floats2half2_rn(dv * CC, dv * CD);                     \
        uint2 o;                                                              \
        o.x = *(unsigned*)&p0;                                                \
        o.y = *(unsigned*)&p1;                                                \
        ntst2u(&th2[(size_t)(gn + r) * 16 + tx], o);                          \
    }
    STORE_ROW(0, c00, c01, c02, c03)
    STORE_ROW(1, c10, c11, c12, c13)
    STORE_ROW(2, c20, c21, c22, c23)
    STORE_ROW(3, c30, c31, c32, c33)
#undef STORE_ROW
}

// ---------------- gather + bias + tanh: 8-deep, index-prefetch, 8 waves/SIMD -
// At the measured floor: ~850k random 128B-line requests per layer at ~25
// outstanding misses/CU (Little's law) == ~40us/gather. Occupancy is the
// only lever that moved it (r6); ILP/balance/capacity-shaping all null.

__device__ __forceinline__ float4 h4tof4(uint2 v) {
    __half2 a = *reinterpret_cast<const __half2*>(&v.x);
    __half2 c = *reinterpret_cast<const __half2*>(&v.y);
    float2 fa = __half22float2(a);
    float2 fc = __half22float2(c);
    return make_float4(fa.x, fa.y, fc.x, fc.y);
}

__device__ __forceinline__ void add4(float4& a, const float4& r) {
    a.x += r.x; a.y += r.y; a.z += r.z; a.w += r.w;
}

__global__ __launch_bounds__(256, 8)
void gather_tanh(const unsigned short* __restrict__ esrc, const int* __restrict__ ideg,
                 const uint2* __restrict__ th2, const float* __restrict__ b,
                 float4* __restrict__ hout4) {
    int tid = threadIdx.x;
    int wid = tid >> 6;
    int lane = tid & 63;
    int sub = lane & 15;   // half4 chunk: dims [4*sub, 4*sub+4)
    int grp = lane >> 4;   // 0..3 -> node
    int node = blockIdx.x * 16 + wid * 4 + grp;  // grid = N_NODES/16 = 3125

    int deg = min(ideg[node], PAD);
    const uint4* ep4 = (const uint4*)(esrc + node * PAD);  // 128B-aligned row
    const uint2* tb = th2 + sub;

    // self-loop + 2 split accumulators
    float4 acc0 = h4tof4(tb[(size_t)node * 16]);
    float4 acc1 = make_float4(0.f, 0.f, 0.f, 0.f);

    int nb = (deg + 7) >> 3;
    uint4 u = (nb > 0) ? ep4[0] : make_uint4(0, 0, 0, 0);  // first index batch
    for (int bi = 0; bi < nb; ++bi) {
        uint4 un = u;
        if (bi + 1 < nb) un = ep4[bi + 1];   // prefetch NEXT indices before rows
        unsigned w[4] = {u.x, u.y, u.z, u.w};
        int idx[8];
#pragma unroll
        for (int j = 0; j < 4; ++j) {
            idx[2 * j + 0] = (int)(w[j] & 0xffffu);
            idx[2 * j + 1] = (int)(w[j] >> 16);
        }
        int rem = deg - bi * 8;
        uint2 r[8];
#pragma unroll
        for (int j = 0; j < 8; ++j) {
            int s = (j < rem) ? idx[j] : ZROW;   // clamp tail to zero row
            r[j] = tb[(size_t)s * 16];
        }
#pragma unroll
        for (int j = 0; j < 8; ++j) {
            float4 v = h4tof4(r[j]);
            if ((j & 1) == 0) add4(acc0, v);
            else              add4(acc1, v);
        }
        u = un;
    }

    float4 acc;
    acc.x = acc0.x + acc1.x;
    acc.y = acc0.y + acc1.y;
    acc.z = acc0.z + acc1.z;
    acc.w = acc0.w + acc1.w;

    float4 bv = ((const float4*)b)[sub];
    float dv = rsqrtf((float)deg + 1.0f);
    float4 res;
    res.x = tanhf(dv * acc.x + bv.x);
    res.y = tanhf(dv * acc.y + bv.y);
    res.z = tanhf(dv * acc.z + bv.z);
    res.w = tanhf(dv * acc.w + bv.w);
    ntst4f(&hout4[(size_t)node * 16 + sub], res);   // consumed by other XCDs
}

// ---------------- pooling + output ----------------

__device__ __forceinline__ int lower_bound(const int* a, int n, int key) {
    int lo = 0, hi = n;
    while (lo < hi) {
        int mid = (lo + hi) >> 1;
        if (a[mid] < key) lo = mid + 1; else hi = mid;
    }
    return lo;
}

__global__ void pool_out(const float* __restrict__ h, const int* __restrict__ batch,
                         const float* __restrict__ Wout, const float* __restrict__ bout,
                         float* __restrict__ out) {
    __shared__ float smax[4][DIM];
    __shared__ float ssum[4][DIM];
    __shared__ int bounds[2];
    int g = blockIdx.x;
    int tid = threadIdx.x, w = tid >> 6, d = tid & 63;
    if (tid == 0) {
        bounds[0] = lower_bound(batch, N_NODES, g);
        bounds[1] = lower_bound(batch, N_NODES, g + 1);
    }
    __syncthreads();
    int start = bounds[0], end = bounds[1];
    float mx = -INFINITY, sum = 0.0f;
    for (int n = start + w; n < end; n += 4) {
        float v = h[(size_t)n * DIM + d];
        mx = fmaxf(mx, v);
        sum += v;
    }
    smax[w][d] = mx;
    ssum[w][d] = sum;
    __syncthreads();
    if (w == 0) {
        mx = fmaxf(fmaxf(smax[0][d], smax[1][d]), fmaxf(smax[2][d], smax[3][d]));
        sum = ssum[0][d] + ssum[1][d] + ssum[2][d] + ssum[3][d];
        float cnt = (float)(end - start);
        float mean = sum / fmaxf(cnt, 1.0f);
        float v = mx * Wout[d] + mean * Wout[DIM + d];
#pragma unroll
        for (int off = 32; off > 0; off >>= 1) v += __shfl_down(v, off, 64);
        if (d == 0) out[g] = v + bout[0];
    }
}

// ---------------- launch ----------------

static inline size_t align256(size_t x) { return (x + 255) & ~(size_t)255; }

extern "C" void kernel_launch(void* const* d_in, const int* in_sizes, int n_in,
                              void* d_out, int out_size, void* d_ws, size_t ws_size,
                              hipStream_t stream) {
    const float* x     = (const float*)d_in[0];
    const int*   ei    = (const int*)d_in[1];
    const int*   batch = (const int*)d_in[2];
    const float* W0    = (const float*)d_in[3];
    const float* b0    = (const float*)d_in[4];
    const float* W1    = (const float*)d_in[5];
    const float* b1    = (const float*)d_in[6];
    const float* W2    = (const float*)d_in[7];
    const float* b2    = (const float*)d_in[8];
    const float* W3    = (const float*)d_in[9];
    const float* b3    = (const float*)d_in[10];
    const float* Wout  = (const float*)d_in[11];
    const float* bout  = (const float*)d_in[12];
    float* out = (float*)d_out;

    const int* row = ei;            // source
    const int* col = ei + N_EDGES;  // destination

    char* ws = (char*)d_ws;
    size_t off = 0;
    int*            ideg = (int*)(ws + off);            off += align256((size_t)N_NODES * 4);
    unsigned short* esrc = (unsigned short*)(ws + off); off += align256((size_t)N_NODES * PAD * 2);
    __half*         th   = (__half*)(ws + off);         off += align256(((size_t)N_NODES + 1) * DIM * 2);
    float*          hA   = (float*)(ws + off);          off += align256((size_t)N_NODES * DIM * 4);
    unsigned*       bbuf = (unsigned*)(ws + off);       off += align256((size_t)NB * CAP_B * 4);
    int*            bcnt = (int*)(ws + off);            off += align256((size_t)NB * 4);
    (void)ws_size;

    const int wave_blocks = N_NODES / 4;                 // 12500 (gemm9)
    const int gath_blocks = N_NODES / 16;                // 3125  (4 nodes/wave)
    const int gemm_blocks = (N_NODES + 63) / 64;         // 782

    // bucketed CSR build (dense writes only)
    hipMemsetAsync(bcnt, 0, (size_t)NB * 4, stream);
    fill_p1<<<NB, 256, 0, stream>>>(row, col, bcnt, bbuf);
    fill_p2<<<NB, 256, 0, stream>>>(bcnt, bbuf, ideg, esrc);

    // layer 0 (gemm9 also zero-fills the ZROW of th)
    gemm9<<<wave_blocks, 256, 0, stream>>>(x, W0, ideg, th);
    gather_tanh<<<gath_blocks, 256, 0, stream>>>(esrc, ideg, (const uint2*)th, b0, (float4*)hA);

    // layers 1-3
    const float* Ws[3] = {W1, W2, W3};
    const float* bs[3] = {b1, b2, b3};
    for (int l = 0; l < 3; ++l) {
        gemm64<<<gemm_blocks, 256, 0, stream>>>(hA, Ws[l], ideg, (uint2*)th);
        gather_tanh<<<gath_blocks, 256, 0, stream>>>(esrc, ideg, (const uint2*)th, bs[l], (float4*)hA);
    }

    // pooling + output
    pool_out<<<N_GRAPHS, 256, 0, stream>>>(hA, batch, Wout, bout, out);
    (void)out_size; (void)n_in; (void)in_sizes;
}